// Round 4
// baseline (751.685 us; speedup 1.0000x reference)
//
#include <hip/hip_runtime.h>

#define BB 1024
#define TT 512
#define KK 64

// Broadcast lane `i`'s value to all lanes via v_readlane (VALU, per-SIMD) —
// deliberately NOT via LDS: the LDS unit is CU-shared and was the round-1..3
// bottleneck (8 waves x 16 ds_read_b128 x ~12cyc ≈ 1540 cyc/step/CU).
__device__ __forceinline__ float bcastf(float x, int i) {
  return __int_as_float(__builtin_amdgcn_readlane(__float_as_int(x), i));
}

// ---- wave(64)-wide reductions via butterfly shuffles (epilogues only) ----
__device__ __forceinline__ float wmaxf(float x) {
#pragma unroll
  for (int off = 32; off > 0; off >>= 1) x = fmaxf(x, __shfl_xor(x, off, 64));
  return x;
}
__device__ __forceinline__ float wsumf(float x) {
#pragma unroll
  for (int off = 32; off > 0; off >>= 1) x += __shfl_xor(x, off, 64);
  return x;
}
__device__ __forceinline__ int wsumi(int x) {
#pragma unroll
  for (int off = 32; off > 0; off >>= 1) x += __shfl_xor(x, off, 64);
  return x;
}

// One forward step: alpha_j <- log(sum_i exp(alpha_i - M) * E[i][j]) + M + em_j
__device__ __forceinline__ void fwd_step(float& alpha, float emv, int m,
                                         const float* Ecol) {
  // Stabilization point: ANY in-range M works (tolerance ~49 abs).
  float M = __int_as_float(__builtin_amdgcn_readfirstlane(__float_as_int(alpha)));
  float pe = __expf(alpha - M);
  float s0 = 0.f, s1 = 0.f, s2 = 0.f, s3 = 0.f;
#pragma unroll
  for (int i = 0; i < KK; i += 4) {
    s0 = fmaf(bcastf(pe, i + 0), Ecol[i + 0], s0);  // v_fmac with SGPR src
    s1 = fmaf(bcastf(pe, i + 1), Ecol[i + 1], s1);
    s2 = fmaf(bcastf(pe, i + 2), Ecol[i + 2], s2);
    s3 = fmaf(bcastf(pe, i + 3), Ecol[i + 3], s3);
  }
  float na = __logf((s0 + s1) + (s2 + s3)) + M + emv;
  alpha = m ? na : alpha;
}

// One viterbi step: best/argmax over i of (v_i + T[i][j]); left-wins-on-'>='
// tournament == np.argmax first-index ties; fmaxf value path is exact, so
// nv = best + em bit-matches the reference recurrence.
__device__ __forceinline__ void vit_step(float& v, float emv, int m,
                                         const float* Tcol,
                                         unsigned char* bpout, int lane) {
  float bv = 0.f; int bx = 0;
#pragma unroll
  for (int ch = 0; ch < 4; ++ch) {
    float tv[8]; int ti[8];
#pragma unroll
    for (int q = 0; q < 8; ++q) {
      const int i0 = ch * 16 + 2 * q, i1 = i0 + 1;
      float a = bcastf(v, i0) + Tcol[i0];  // v_add with SGPR src
      float c = bcastf(v, i1) + Tcol[i1];
      tv[q] = fmaxf(a, c);
      ti[q] = (a >= c) ? i0 : i1;
    }
#pragma unroll
    for (int w = 4; w >= 1; w >>= 1) {
#pragma unroll
      for (int q = 0; q < w; ++q) {   // in-place compaction is read-safe
        ti[q] = (tv[2 * q] >= tv[2 * q + 1]) ? ti[2 * q] : ti[2 * q + 1];
        tv[q] = fmaxf(tv[2 * q], tv[2 * q + 1]);
      }
    }
    if (ch == 0) { bv = tv[0]; bx = ti[0]; }
    else { bx = (bv >= tv[0]) ? bx : ti[0]; bv = fmaxf(bv, tv[0]); }
  }
  *bpout = (unsigned char)(m ? bx : lane);
  v = m ? (bv + emv) : v;
}

// One block = one batch element. 128 threads = 2 waves:
//   wave0: forward (logZ) + gold score -> nll ;  wave1: viterbi + backtrace.
// No LDS in the recurrence loops except the 1-byte bp store.
extern "C" __global__ void __launch_bounds__(128, 2) crf_all_kernel(
    const float* __restrict__ em,      // [B,T,K]
    const int* __restrict__ tags,      // [B,T]
    const int* __restrict__ mask,      // [B,T]
    const float* __restrict__ trans,   // [K,K]
    const float* __restrict__ startt,  // [K]
    const float* __restrict__ endt,    // [K]
    float* __restrict__ out) {         // [B] nll ++ [B,T] path (as float)
  __shared__ unsigned char bp[(TT - 1) * KK];  // 32704 B backpointers

  const int b = blockIdx.x;
  const int lane = threadIdx.x & 63;
  const float* emb = em + (size_t)b * TT * KK;
  const int* maskb = mask + b * TT;
  const int* tagsb = tags + b * TT;

  if (threadIdx.x < 64) {
    // ---------------- wave0: forward (logZ) + gold score ----------------
    float Ecol[KK];  // lane j holds column j of E = exp(trans)
#pragma unroll
    for (int i = 0; i < KK; ++i) Ecol[i] = __expf(trans[i * KK + lane]);

    float alpha = startt[lane] + emb[lane];
    // 4-step software pipeline on emissions+mask (hides HBM latency).
    float pe[4]; int pm[4];
#pragma unroll
    for (int k = 0; k < 4; ++k) {
      int tl = 1 + k;
      pe[k] = emb[tl * KK + lane];
      pm[k] = maskb[tl];
    }
    int t = 1;
#pragma unroll 1
    for (int g = 0; g < 127; ++g) {   // steps t = 1..508
      float ne[4]; int nm[4];
#pragma unroll
      for (int k = 0; k < 4; ++k) {
        int tl = t + 4 + k; tl = (tl < TT) ? tl : (TT - 1);
        ne[k] = emb[(size_t)tl * KK + lane];
        nm[k] = maskb[tl];
      }
#pragma unroll
      for (int k = 0; k < 4; ++k) fwd_step(alpha, pe[k], pm[k], Ecol);
      t += 4;
#pragma unroll
      for (int k = 0; k < 4; ++k) { pe[k] = ne[k]; pm[k] = nm[k]; }
    }
#pragma unroll
    for (int k = 0; k < 3; ++k) fwd_step(alpha, pe[k], pm[k], Ecol);  // 509..511

    // logZ = logsumexp(alpha + end) — exact max (runs once)
    float x = alpha + endt[lane];
    float M2 = wmaxf(x);
    float S = wsumf(__expf(x - M2));
    float logZ = __logf(S) + M2;

    // gold score: lane j covers t = u*64 + j
    float acc = 0.f;
    int msum = 0;
#pragma unroll
    for (int u = 0; u < TT / KK; ++u) {
      int t2 = u * KK + lane;
      int tg = tagsb[t2];
      int m = maskb[t2];
      msum += m;
      float mf = (float)m;
      acc = fmaf(emb[(size_t)t2 * KK + tg], mf, acc);
      if (t2 >= 1) acc = fmaf(trans[tagsb[t2 - 1] * KK + tg], mf, acc);
    }
    acc = wsumf(acc);
    msum = wsumi(msum);
    if (lane == 0) {
      float gold = acc + startt[tagsb[0]] + endt[tagsb[msum - 1]];
      out[b] = logZ - gold;
    }
  } else {
    // ---------------- wave1: viterbi + backtrace ----------------
    float Tcol[KK];  // lane j holds column j of trans
#pragma unroll
    for (int i = 0; i < KK; ++i) Tcol[i] = trans[i * KK + lane];

    float v = startt[lane] + emb[lane];
    float pe[4]; int pm[4];
#pragma unroll
    for (int k = 0; k < 4; ++k) {
      int tl = 1 + k;
      pe[k] = emb[tl * KK + lane];
      pm[k] = maskb[tl];
    }
    int t = 1;
#pragma unroll 1
    for (int g = 0; g < 127; ++g) {   // steps t = 1..508
      float ne[4]; int nm[4];
#pragma unroll
      for (int k = 0; k < 4; ++k) {
        int tl = t + 4 + k; tl = (tl < TT) ? tl : (TT - 1);
        ne[k] = emb[(size_t)tl * KK + lane];
        nm[k] = maskb[tl];
      }
#pragma unroll
      for (int k = 0; k < 4; ++k)
        vit_step(v, pe[k], pm[k], Tcol, &bp[(t - 1 + k) * KK + lane], lane);
      t += 4;
#pragma unroll
      for (int k = 0; k < 4; ++k) { pe[k] = ne[k]; pm[k] = nm[k]; }
    }
#pragma unroll
    for (int k = 0; k < 3; ++k)
      vit_step(v, pe[k], pm[k], Tcol, &bp[(t - 1 + k) * KK + lane], lane);

    // last = argmax(v + end), first-index on exact ties (runs once)
    float sc = v + endt[lane];
    int idx = lane;
#pragma unroll
    for (int off = 32; off > 0; off >>= 1) {
      float osc = __shfl_xor(sc, off, 64);
      int oidx = __shfl_xor(idx, off, 64);
      if (osc > sc || (osc == sc && oidx < idx)) { sc = osc; idx = oidx; }
    }
    // backtrace: uniform LDS pointer chase
    int tag = idx;
    float* pout = out + BB + (size_t)b * TT;
    for (int tt = TT - 1; tt >= 1; --tt) {
      if (lane == 0) pout[tt] = (float)tag;
      tag = bp[(tt - 1) * KK + tag];
    }
    if (lane == 0) pout[0] = (float)tag;
  }
}

extern "C" void kernel_launch(void* const* d_in, const int* in_sizes, int n_in,
                              void* d_out, int out_size, void* d_ws, size_t ws_size,
                              hipStream_t stream) {
  (void)in_sizes; (void)n_in; (void)out_size; (void)d_ws; (void)ws_size;
  const float* em = (const float*)d_in[0];
  const int* tags = (const int*)d_in[1];
  const int* mask = (const int*)d_in[2];
  const float* trans = (const float*)d_in[3];
  const float* startt = (const float*)d_in[4];
  const float* endt = (const float*)d_in[5];
  float* out = (float*)d_out;
  crf_all_kernel<<<dim3(BB), dim3(128), 0, stream>>>(em, tags, mask, trans,
                                                     startt, endt, out);
}

// Round 5
// 682.871 us; speedup vs baseline: 1.1008x; 1.1008x over previous
//
#include <hip/hip_runtime.h>

#define BB 1024
#define TT 512
#define KK 64

// ---- wave(64)-wide reductions via butterfly shuffles (epilogues only) ----
__device__ __forceinline__ float wmaxf(float x) {
#pragma unroll
  for (int off = 32; off > 0; off >>= 1) x = fmaxf(x, __shfl_xor(x, off, 64));
  return x;
}
__device__ __forceinline__ float wsumf(float x) {
#pragma unroll
  for (int off = 32; off > 0; off >>= 1) x += __shfl_xor(x, off, 64);
  return x;
}
__device__ __forceinline__ int wsumi(int x) {
#pragma unroll
  for (int off = 32; off > 0; off >>= 1) x += __shfl_xor(x, off, 64);
  return x;
}

// One block = one batch element. 128 threads = 2 waves:
//   wave0: forward algorithm (logZ) + gold score -> nll = logZ - gold
//   wave1: viterbi recurrence (bp packed in LDS) + backtrace -> path
// Disjoint LDS buffers, no inter-wave sync. The CU-shared LDS pipe is the
// measured wall -> minimize LDS instructions per step:
//   wave0: 1 ds_write_b16 + 8 ds_read_b128 (bf16 broadcast)
//   wave1: 1 ds_write_b32 + 16 ds_read_b128 (fp32, exactness) + b32/4steps
extern "C" __global__ void __launch_bounds__(128) crf_all_kernel(
    const float* __restrict__ em,      // [B,T,K]
    const int* __restrict__ tags,      // [B,T]
    const int* __restrict__ mask,      // [B,T]
    const float* __restrict__ trans,   // [K,K]
    const float* __restrict__ startt,  // [K]
    const float* __restrict__ endt,    // [K]
    float* __restrict__ out) {         // [B] nll ++ [B,T] path (as float)
  __shared__ unsigned int bp32[(TT / 4) * KK];       // 32768 B packed backptrs
  __shared__ __align__(16) unsigned short pbuf[KK];  // fwd p as bf16 (128 B)
  __shared__ __align__(16) float vbuf[KK];           // viterbi v (256 B)

  const int b = blockIdx.x;
  const int lane = threadIdx.x & 63;
  const float* emb = em + (size_t)b * TT * KK;
  const int* maskb = mask + b * TT;
  const int* tagsb = tags + b * TT;

  if (threadIdx.x < 64) {
    // ---------------- wave0: forward (logZ) + gold score ----------------
    float Ecol[KK];  // lane j holds column j of E = exp(trans)
#pragma unroll
    for (int i = 0; i < KK; ++i) Ecol[i] = __expf(trans[i * KK + lane]);

    float alpha = startt[lane] + emb[lane];
#pragma unroll 1
    for (int t = 1; t < TT; ++t) {
      float emv = emb[t * KK + lane];  // coalesced, issued early
      int m = maskb[t];
      // Stabilization point: ANY in-range M works (tolerance ~49 abs);
      // readfirstlane avoids 6 LDS-pipe shuffle ops per step.
      float M = __int_as_float(__builtin_amdgcn_readfirstlane(__float_as_int(alpha)));
      float p = __expf(alpha - M);
      // bf16-truncate p: halves the broadcast to 8 ds_read_b128.
      pbuf[lane] = (unsigned short)(__float_as_uint(p) >> 16);
      __builtin_amdgcn_wave_barrier();  // same-wave LDS in-order; fence compiler
      float s0 = 0.f, s1 = 0.f, s2 = 0.f, s3 = 0.f;
      const uint4* pb4 = (const uint4*)pbuf;
#pragma unroll
      for (int q = 0; q < 8; ++q) {
        uint4 d = pb4[q];  // same-address broadcast ds_read_b128, 8 bf16
        s0 = fmaf(__uint_as_float(d.x << 16), Ecol[8 * q + 0], s0);
        s1 = fmaf(__uint_as_float(d.x & 0xFFFF0000u), Ecol[8 * q + 1], s1);
        s2 = fmaf(__uint_as_float(d.y << 16), Ecol[8 * q + 2], s2);
        s3 = fmaf(__uint_as_float(d.y & 0xFFFF0000u), Ecol[8 * q + 3], s3);
        s0 = fmaf(__uint_as_float(d.z << 16), Ecol[8 * q + 4], s0);
        s1 = fmaf(__uint_as_float(d.z & 0xFFFF0000u), Ecol[8 * q + 5], s1);
        s2 = fmaf(__uint_as_float(d.w << 16), Ecol[8 * q + 6], s2);
        s3 = fmaf(__uint_as_float(d.w & 0xFFFF0000u), Ecol[8 * q + 7], s3);
      }
      __builtin_amdgcn_wave_barrier();
      float na = __logf((s0 + s1) + (s2 + s3)) + M + emv;
      alpha = (m != 0) ? na : alpha;
    }
    // logZ = logsumexp(alpha + end) — exact max (runs once)
    float x = alpha + endt[lane];
    float M2 = wmaxf(x);
    float S = wsumf(__expf(x - M2));
    float logZ = __logf(S) + M2;

    // gold score: lane j covers t = u*64 + j
    float acc = 0.f;
    int msum = 0;
#pragma unroll
    for (int u = 0; u < TT / KK; ++u) {
      int t2 = u * KK + lane;
      int tg = tagsb[t2];
      int m = maskb[t2];
      msum += m;
      float mf = (float)m;
      acc = fmaf(emb[(size_t)t2 * KK + tg], mf, acc);
      if (t2 >= 1) acc = fmaf(trans[tagsb[t2 - 1] * KK + tg], mf, acc);
    }
    acc = wsumf(acc);
    msum = wsumi(msum);
    if (lane == 0) {
      float gold = acc + startt[tagsb[0]] + endt[tagsb[msum - 1]];
      out[b] = logZ - gold;
    }
  } else {
    // ---------------- wave1: viterbi + backtrace ----------------
    float Tcol[KK];  // lane j holds column j of trans
#pragma unroll
    for (int i = 0; i < KK; ++i) Tcol[i] = trans[i * KK + lane];

    float v = startt[lane] + emb[lane];
    unsigned int pk = 0;  // 4 packed backpointer bytes
#pragma unroll 1
    for (int t = 1; t < TT; ++t) {
      float emv = emb[t * KK + lane];
      int m = maskb[t];
      vbuf[lane] = v;
      __builtin_amdgcn_wave_barrier();
      float best = -3.402823466e38f;
      int bi = 0;
      // ascending i + strict '>' == np.argmax first-index tie-break.
      // scores are plain fp32 adds -> bitwise-matches reference recurrence.
#pragma unroll
      for (int i = 0; i < KK; i += 4) {
        float4 vv = *(const float4*)&vbuf[i];  // broadcast ds_read_b128
        float c0 = vv.x + Tcol[i + 0];
        float c1 = vv.y + Tcol[i + 1];
        float c2 = vv.z + Tcol[i + 2];
        float c3 = vv.w + Tcol[i + 3];
        if (c0 > best) { best = c0; bi = i + 0; }
        if (c1 > best) { best = c1; bi = i + 1; }
        if (c2 > best) { best = c2; bi = i + 2; }
        if (c3 > best) { best = c3; bi = i + 3; }
      }
      __builtin_amdgcn_wave_barrier();
      int bq = (m != 0) ? bi : lane;
      const int idx = t - 1;                 // 0..510
      pk |= (unsigned int)bq << (8 * (idx & 3));
      if ((idx & 3) == 3) {                  // wave-uniform branch
        bp32[(idx >> 2) * KK + lane] = pk;   // conflict-free stride-1 dwords
        pk = 0;
      }
      v = (m != 0) ? (best + emv) : v;
    }
    bp32[(510 >> 2) * KK + lane] = pk;  // flush group 127 (3 valid bytes)

    // last = argmax(v + end), first-index on exact ties (runs once)
    float sc = v + endt[lane];
    int idx = lane;
#pragma unroll
    for (int off = 32; off > 0; off >>= 1) {
      float osc = __shfl_xor(sc, off, 64);
      int oidx = __shfl_xor(idx, off, 64);
      if (osc > sc || (osc == sc && oidx < idx)) { sc = osc; idx = oidx; }
    }
    // backtrace: uniform LDS pointer chase through packed bytes
    int tag = idx;
    float* pout = out + BB + (size_t)b * TT;
    for (int tt = TT - 1; tt >= 1; --tt) {
      if (lane == 0) pout[tt] = (float)tag;
      const int e = tt - 1;
      unsigned int w = bp32[(e >> 2) * KK + tag];
      tag = (int)((w >> (8 * (e & 3))) & 0xFFu);
    }
    if (lane == 0) pout[0] = (float)tag;
  }
}

extern "C" void kernel_launch(void* const* d_in, const int* in_sizes, int n_in,
                              void* d_out, int out_size, void* d_ws, size_t ws_size,
                              hipStream_t stream) {
  (void)in_sizes; (void)n_in; (void)out_size; (void)d_ws; (void)ws_size;
  const float* em = (const float*)d_in[0];
  const int* tags = (const int*)d_in[1];
  const int* mask = (const int*)d_in[2];
  const float* trans = (const float*)d_in[3];
  const float* startt = (const float*)d_in[4];
  const float* endt = (const float*)d_in[5];
  float* out = (float*)d_out;
  crf_all_kernel<<<dim3(BB), dim3(128), 0, stream>>>(em, tags, mask, trans,
                                                     startt, endt, out);
}

// Round 6
// 547.158 us; speedup vs baseline: 1.3738x; 1.2480x over previous
//
#include <hip/hip_runtime.h>

#define BB 1024
#define TT 512
#define KK 64

// ---- wave(64)-wide reductions via butterfly shuffles (epilogues only) ----
__device__ __forceinline__ float wmaxf(float x) {
#pragma unroll
  for (int off = 32; off > 0; off >>= 1) x = fmaxf(x, __shfl_xor(x, off, 64));
  return x;
}
__device__ __forceinline__ float wsumf(float x) {
#pragma unroll
  for (int off = 32; off > 0; off >>= 1) x += __shfl_xor(x, off, 64);
  return x;
}
__device__ __forceinline__ int wsumi(int x) {
#pragma unroll
  for (int off = 32; off > 0; off >>= 1) x += __shfl_xor(x, off, 64);
  return x;
}

// One block = one batch element. 128 threads = 2 waves:
//   wave0: forward algorithm (logZ) + gold score -> nll = logZ - gold
//   wave1: viterbi recurrence (bp in LDS) + backtrace -> path
// R1 structure restored verbatim (no unroll pragmas on the T-loops: the
// compiler's own unrolling pipelines the per-step emv/mask HBM loads — every
// round that pinned unroll(1) regressed). Only two chain cuts vs R1:
// readfirstlane stabilizer (wave0) and a split dual argmax scan (wave1).
extern "C" __global__ void __launch_bounds__(128) crf_all_kernel(
    const float* __restrict__ em,      // [B,T,K]
    const int* __restrict__ tags,      // [B,T]
    const int* __restrict__ mask,      // [B,T]
    const float* __restrict__ trans,   // [K,K]
    const float* __restrict__ startt,  // [K]
    const float* __restrict__ endt,    // [K]
    float* __restrict__ out) {         // [B] nll ++ [B,T] path (as float)
  __shared__ unsigned char bp[(TT - 1) * KK];     // 32704 B backpointers
  __shared__ __align__(16) float pbuf[KK];        // forward exp(alpha-M)
  __shared__ __align__(16) float vbuf[KK];        // viterbi v broadcast

  const int b = blockIdx.x;
  const int lane = threadIdx.x & 63;
  const float* emb = em + (size_t)b * TT * KK;
  const int* maskb = mask + b * TT;
  const int* tagsb = tags + b * TT;

  if (threadIdx.x < 64) {
    // ---------------- wave0: forward (logZ) + gold score ----------------
    float Ecol[KK];  // lane j holds column j of E = exp(trans)
#pragma unroll
    for (int i = 0; i < KK; ++i) Ecol[i] = __expf(trans[i * KK + lane]);

    float alpha = startt[lane] + emb[lane];
    for (int t = 1; t < TT; ++t) {
      float emv = emb[t * KK + lane];  // coalesced, issued early
      int m = maskb[t];
      // Stabilization point: ANY in-range M works (tolerance ~49 abs);
      // readfirstlane replaces the 6-deep ds_swizzle butterfly (absmax was
      // 0.0 with this in rounds 2-4).
      float M = __int_as_float(__builtin_amdgcn_readfirstlane(__float_as_int(alpha)));
      pbuf[lane] = __expf(alpha - M);
      __builtin_amdgcn_wave_barrier();  // same-wave LDS in-order; fence compiler
      float s0 = 0.f, s1 = 0.f, s2 = 0.f, s3 = 0.f;
#pragma unroll
      for (int i = 0; i < KK; i += 4) {
        float4 pv = *(const float4*)&pbuf[i];  // same-address broadcast ds_read_b128
        s0 = fmaf(pv.x, Ecol[i + 0], s0);
        s1 = fmaf(pv.y, Ecol[i + 1], s1);
        s2 = fmaf(pv.z, Ecol[i + 2], s2);
        s3 = fmaf(pv.w, Ecol[i + 3], s3);
      }
      __builtin_amdgcn_wave_barrier();
      float na = __logf((s0 + s1) + (s2 + s3)) + M + emv;
      alpha = (m != 0) ? na : alpha;
    }
    // logZ = logsumexp(alpha + end) — exact max (runs once)
    float x = alpha + endt[lane];
    float M2 = wmaxf(x);
    float S = wsumf(__expf(x - M2));
    float logZ = __logf(S) + M2;

    // gold score: lane j covers t = u*64 + j
    float acc = 0.f;
    int msum = 0;
#pragma unroll
    for (int u = 0; u < TT / KK; ++u) {
      int t2 = u * KK + lane;
      int tg = tagsb[t2];
      int m = maskb[t2];
      msum += m;
      float mf = (float)m;
      acc = fmaf(emb[(size_t)t2 * KK + tg], mf, acc);
      if (t2 >= 1) acc = fmaf(trans[tagsb[t2 - 1] * KK + tg], mf, acc);
    }
    acc = wsumf(acc);
    msum = wsumi(msum);
    if (lane == 0) {
      float gold = acc + startt[tagsb[0]] + endt[tagsb[msum - 1]];
      out[b] = logZ - gold;
    }
  } else {
    // ---------------- wave1: viterbi + backtrace ----------------
    float Tcol[KK];  // lane j holds column j of trans
#pragma unroll
    for (int i = 0; i < KK; ++i) Tcol[i] = trans[i * KK + lane];

    float v = startt[lane] + emb[lane];
    for (int t = 1; t < TT; ++t) {
      float emv = emb[t * KK + lane];
      int m = maskb[t];
      vbuf[lane] = v;
      __builtin_amdgcn_wave_barrier();
      // Two independent 32-deep strict-'>' scans (halved dependency chain),
      // merged low-wins-on-'>=' == np.argmax first-index tie-break. Scores
      // are plain fp32 adds -> bitwise-matches the reference recurrence.
      float bestL = -3.402823466e38f, bestH = -3.402823466e38f;
      int biL = 0, biH = 32;
#pragma unroll
      for (int i = 0; i < 32; i += 4) {
        float4 lo = *(const float4*)&vbuf[i];       // broadcast ds_read_b128
        float4 hi = *(const float4*)&vbuf[i + 32];  // broadcast ds_read_b128
        float l0 = lo.x + Tcol[i + 0];
        float l1 = lo.y + Tcol[i + 1];
        float l2 = lo.z + Tcol[i + 2];
        float l3 = lo.w + Tcol[i + 3];
        float h0 = hi.x + Tcol[i + 32];
        float h1 = hi.y + Tcol[i + 33];
        float h2 = hi.z + Tcol[i + 34];
        float h3 = hi.w + Tcol[i + 35];
        if (l0 > bestL) { bestL = l0; biL = i + 0; }
        if (l1 > bestL) { bestL = l1; biL = i + 1; }
        if (l2 > bestL) { bestL = l2; biL = i + 2; }
        if (l3 > bestL) { bestL = l3; biL = i + 3; }
        if (h0 > bestH) { bestH = h0; biH = i + 32; }
        if (h1 > bestH) { bestH = h1; biH = i + 33; }
        if (h2 > bestH) { bestH = h2; biH = i + 34; }
        if (h3 > bestH) { bestH = h3; biH = i + 35; }
      }
      int bi = (bestL >= bestH) ? biL : biH;  // low half wins exact ties
      float best = fmaxf(bestL, bestH);
      __builtin_amdgcn_wave_barrier();
      bp[(t - 1) * KK + lane] = (unsigned char)((m != 0) ? bi : lane);
      v = (m != 0) ? (best + emv) : v;
    }
    // last = argmax(v + end), first-index on exact ties (runs once)
    float sc = v + endt[lane];
    int idx = lane;
#pragma unroll
    for (int off = 32; off > 0; off >>= 1) {
      float osc = __shfl_xor(sc, off, 64);
      int oidx = __shfl_xor(idx, off, 64);
      if (osc > sc || (osc == sc && oidx < idx)) { sc = osc; idx = oidx; }
    }
    // backtrace: uniform LDS pointer chase
    int tag = idx;
    float* pout = out + BB + (size_t)b * TT;
    for (int tt = TT - 1; tt >= 1; --tt) {
      if (lane == 0) pout[tt] = (float)tag;
      tag = bp[(tt - 1) * KK + tag];
    }
    if (lane == 0) pout[0] = (float)tag;
  }
}

extern "C" void kernel_launch(void* const* d_in, const int* in_sizes, int n_in,
                              void* d_out, int out_size, void* d_ws, size_t ws_size,
                              hipStream_t stream) {
  (void)in_sizes; (void)n_in; (void)out_size; (void)d_ws; (void)ws_size;
  const float* em = (const float*)d_in[0];
  const int* tags = (const int*)d_in[1];
  const int* mask = (const int*)d_in[2];
  const float* trans = (const float*)d_in[3];
  const float* startt = (const float*)d_in[4];
  const float* endt = (const float*)d_in[5];
  float* out = (float*)d_out;
  crf_all_kernel<<<dim3(BB), dim3(128), 0, stream>>>(em, tags, mask, trans,
                                                     startt, endt, out);
}